// Round 5
// baseline (608.266 us; speedup 1.0000x reference)
//
#include <hip/hip_runtime.h>
#include <hip/hip_bf16.h>

#define HDIM 64
#define LSEQ 1024
#define NB 64
#define NV 32000
#define CC 32            // chunk length
#define NCH 32           // chunks per sequence
#define NT (NB * LSEQ)   // total tokens = kallT row stride

// ---------- DPP cross-lane sums (pure VALU) ----------
template<int CTRL>
__device__ __forceinline__ float dpp_red(float x) {
  int y = __builtin_amdgcn_update_dpp(0, __float_as_int(x), CTRL, 0xF, 0xF, true);
  return x + __int_as_float(y);
}
// quad sum (over lanes xor 1, xor 2)
__device__ __forceinline__ float quad_sum(float x) {
  x = dpp_red<0xB1>(x);
  x = dpp_red<0x4E>(x);
  return x;
}
// full 64-lane sum, uniform result
__device__ __forceinline__ float wave_sum(float x) {
  x = dpp_red<0xB1>(x);    // xor 1
  x = dpp_red<0x4E>(x);    // xor 2
  x = dpp_red<0x141>(x);   // row_half_mirror -> sum of 8
  x = dpp_red<0x140>(x);   // row_mirror      -> sum of 16
  float a = __int_as_float(__builtin_amdgcn_readlane(__float_as_int(x), 0));
  float b = __int_as_float(__builtin_amdgcn_readlane(__float_as_int(x), 16));
  float c = __int_as_float(__builtin_amdgcn_readlane(__float_as_int(x), 32));
  float d = __int_as_float(__builtin_amdgcn_readlane(__float_as_int(x), 48));
  return (a + b) + (c + d);
}

// ---------- Kernel 0: transpose W1 (64x128 -> 128x64) and kpW (64x64) ----------
__global__ __launch_bounds__(256) void transpose_w(const float* __restrict__ W1,
    const float* __restrict__ kpW, float* __restrict__ W1T, float* __restrict__ kpWT)
{
  const int tid = blockIdx.x * 256 + threadIdx.x;   // grid 48 -> 12288 threads
  if (tid < 8192) { const int c = tid >> 6, j = tid & 63; W1T[tid] = W1[j * 128 + c]; }
  else { const int e = tid - 8192; const int i = e >> 6, j = e & 63; kpWT[e] = kpW[j * 64 + i]; }
}

// ---------- Kernel 1: token transform, lane = token; weights via scalar cache ----------
__global__ __launch_bounds__(256) void tok4(
    const int* __restrict__ seq, const float* __restrict__ embed,
    const float* __restrict__ W1T, const float* __restrict__ b1,
    const float* __restrict__ W2, const float* __restrict__ b2,
    const float* __restrict__ gamma, const float* __restrict__ beta,
    const float* __restrict__ kpWT, float* __restrict__ kallT,
    float* __restrict__ thr2_all, float* __restrict__ inv_all)
{
  const int tok = blockIdx.x * 256 + threadIdx.x;
  const int row = seq[tok];
  float h[64], x[64];
  const float4* ep = (const float4*)(embed + (size_t)row * HDIM);
  #pragma unroll
  for (int q = 0; q < 16; ++q) {
    const float4 v = ep[q];
    h[4*q] = v.x; h[4*q+1] = v.y; h[4*q+2] = v.z; h[4*q+3] = v.w;
  }
  #pragma unroll
  for (int j = 0; j < 64; ++j) x[j] = h[j] + b2[j];   // uniform s_load

  for (int c = 0; c < 128; ++c) {
    const float* w1r = W1T + c * 64;                   // uniform row -> s_load
    float a0 = 0.f, a1 = 0.f, a2 = 0.f, a3 = 0.f;
    #pragma unroll
    for (int j = 0; j < 64; j += 4) {
      a0 = fmaf(h[j],   w1r[j],   a0);
      a1 = fmaf(h[j+1], w1r[j+1], a1);
      a2 = fmaf(h[j+2], w1r[j+2], a2);
      a3 = fmaf(h[j+3], w1r[j+3], a3);
    }
    const float y = fmaxf(b1[c] + ((a0 + a1) + (a2 + a3)), 0.f);
    const float* w2r = W2 + c * 64;                    // uniform row -> s_load
    #pragma unroll
    for (int j = 0; j < 64; ++j) x[j] = fmaf(y, w2r[j], x[j]);
  }

  // layernorm (per-lane)
  float s0=0.f,s1=0.f,s2=0.f,s3=0.f,q0=0.f,q1=0.f,q2=0.f,q3=0.f;
  #pragma unroll
  for (int j = 0; j < 64; j += 4) {
    s0 += x[j]; s1 += x[j+1]; s2 += x[j+2]; s3 += x[j+3];
    q0 = fmaf(x[j],   x[j],   q0); q1 = fmaf(x[j+1], x[j+1], q1);
    q2 = fmaf(x[j+2], x[j+2], q2); q3 = fmaf(x[j+3], x[j+3], q3);
  }
  const float mu  = ((s0+s1)+(s2+s3)) * (1.f/64.f);
  const float var = ((q0+q1)+(q2+q3)) * (1.f/64.f) - mu * mu;
  const float rs  = rsqrtf(var + 1e-5f);
  #pragma unroll
  for (int j = 0; j < 64; ++j) h[j] = (x[j] - mu) * rs * gamma[j] + beta[j];

  // k projection; store transposed (coalesced across lanes)
  float nk2 = 0.f;
  for (int i = 0; i < 64; ++i) {
    const float* kr = kpWT + i * 64;                   // uniform row -> s_load
    float c0=0.f,c1=0.f,c2=0.f,c3=0.f;
    #pragma unroll
    for (int j = 0; j < 64; j += 4) {
      c0 = fmaf(h[j],   kr[j],   c0);
      c1 = fmaf(h[j+1], kr[j+1], c1);
      c2 = fmaf(h[j+2], kr[j+2], c2);
      c3 = fmaf(h[j+3], kr[j+3], c3);
    }
    const float ki = (c0 + c1) + (c2 + c3);
    nk2 = fmaf(ki, ki, nk2);
    kallT[(size_t)i * NT + tok] = ki;
  }
  thr2_all[tok] = 0.16f * nk2;                         // (0.4*||k||)^2
  inv_all[tok]  = 1.f / fmaxf(sqrtf(nk2), 1e-12f);
}

// ---------- Kernel 2: per-chunk normalized Gram, direct from global (1 wave/block) ----------
__global__ __launch_bounds__(64) void gram2(const float* __restrict__ kallT,
    const float* __restrict__ inv_all, float* __restrict__ Gg)
{
  const int bi = blockIdx.x;               // grid NB*NCH
  const int b = bi >> 5, ch = bi & 31;
  const int l = threadIdx.x;
  const int t0 = (l & 7) * 4, s0 = (l >> 3) * 4;
  const size_t gb = (size_t)b * LSEQ + ch * CC;
  float g00=0,g01=0,g02=0,g03=0, g10=0,g11=0,g12=0,g13=0;
  float g20=0,g21=0,g22=0,g23=0, g30=0,g31=0,g32=0,g33=0;
  for (int j = 0; j < 64; ++j) {
    const float* rowp = kallT + (size_t)j * NT + gb;
    const float4 a = *(const float4*)(rowp + t0);
    const float4 c = *(const float4*)(rowp + s0);
    g00=fmaf(a.x,c.x,g00); g01=fmaf(a.x,c.y,g01); g02=fmaf(a.x,c.z,g02); g03=fmaf(a.x,c.w,g03);
    g10=fmaf(a.y,c.x,g10); g11=fmaf(a.y,c.y,g11); g12=fmaf(a.y,c.z,g12); g13=fmaf(a.y,c.w,g13);
    g20=fmaf(a.z,c.x,g20); g21=fmaf(a.z,c.y,g21); g22=fmaf(a.z,c.z,g22); g23=fmaf(a.z,c.w,g23);
    g30=fmaf(a.w,c.x,g30); g31=fmaf(a.w,c.y,g31); g32=fmaf(a.w,c.z,g32); g33=fmaf(a.w,c.w,g33);
  }
  const float4 it = *(const float4*)(inv_all + gb + t0);
  const float4 is = *(const float4*)(inv_all + gb + s0);
  float* Go = Gg + (size_t)bi * (CC * CC);
  float4 o;
  o.x=g00*it.x*is.x; o.y=g01*it.x*is.y; o.z=g02*it.x*is.z; o.w=g03*it.x*is.w;
  *(float4*)(Go + (t0+0)*CC + s0) = o;
  o.x=g10*it.y*is.x; o.y=g11*it.y*is.y; o.z=g12*it.y*is.z; o.w=g13*it.y*is.w;
  *(float4*)(Go + (t0+1)*CC + s0) = o;
  o.x=g20*it.z*is.x; o.y=g21*it.z*is.y; o.z=g22*it.z*is.z; o.w=g23*it.z*is.w;
  *(float4*)(Go + (t0+2)*CC + s0) = o;
  o.x=g30*it.w*is.x; o.y=g31*it.w*is.y; o.z=g32*it.w*is.z; o.w=g33*it.w*is.w;
  *(float4*)(Go + (t0+3)*CC + s0) = o;
}

// ---------- Kernel 3: chunked gated delta scan, 3 waves ----------
// wave 0: serial gate core (B) + next-chunk staging; waves 1-2: helpers,
// each owning 32 M rows as 2 rows x 16 cols per lane (quad-DPP reduction).
__global__ __launch_bounds__(192, 1) void scan5(
    const float* __restrict__ kallT, const float* __restrict__ thr2_all,
    const float* __restrict__ inv_all, const float* __restrict__ Gg,
    float* __restrict__ readv)
{
  __shared__ float kS[3][CC * 68];     // k chunks [t][j], pad 68
  __shared__ float GS[2][CC * CC];
  __shared__ float rS[CC * 64];        // scaled base (M k_t)*inv_t per feature
  __shared__ float cstS[CC * 64];      // gated raw err
  __shared__ float thr2S[2][CC];
  __shared__ float invS[3][CC];

  const int b = blockIdx.x, tid = threadIdx.x;
  const int w = tid >> 6, l = tid & 63;
  const int A = l >> 2, B4 = l & 3;
  const int r0 = 32 * (w - 1) + 2 * A;   // helper rows (valid for w>0)
  const int jb = 16 * B4;                // col slice base
  const size_t gbase = (size_t)b * LSEQ;

  float M0[16], M1[16];
  #pragma unroll
  for (int q = 0; q < 16; ++q) { M0[q] = 0.f; M1[q] = 0.f; }

  // ---- prologue: stage chunk 0 ----
  if (w < 2) {
    const float* src = kallT + (size_t)l * NT + gbase + w * 16;
    #pragma unroll
    for (int q = 0; q < 4; ++q) {
      const float4 v = ((const float4*)src)[q];
      const int t0 = w * 16 + q * 4;
      kS[0][(t0+0)*68 + l] = v.x; kS[0][(t0+1)*68 + l] = v.y;
      kS[0][(t0+2)*68 + l] = v.z; kS[0][(t0+3)*68 + l] = v.w;
    }
  } else {
    const float4* gsrc = (const float4*)(Gg + (size_t)b * NCH * (CC * CC));
    #pragma unroll
    for (int q = 0; q < 4; ++q) ((float4*)GS[0])[q * 64 + l] = gsrc[q * 64 + l];
    if (l < CC) thr2S[0][l] = thr2_all[gbase + l];
    else        invS[0][l - CC] = inv_all[gbase + (l - CC)];
  }
  __syncthreads();

  for (int ch = 0; ch < NCH; ++ch) {
    const int cb = ch % 3, pb = (ch + 2) % 3, nb = (ch + 1) % 3;
    const int cg = ch & 1, ng = (ch + 1) & 1;

    // ---- phase H ----
    if (w == 0) {
      if (ch < NCH - 1) {     // stage chunk ch+1
        const float* src = kallT + (size_t)l * NT + gbase + (ch + 1) * CC;
        #pragma unroll
        for (int q = 0; q < 8; ++q) {
          const float4 v = ((const float4*)src)[q];
          const int t0 = q * 4;
          kS[nb][(t0+0)*68 + l] = v.x; kS[nb][(t0+1)*68 + l] = v.y;
          kS[nb][(t0+2)*68 + l] = v.z; kS[nb][(t0+3)*68 + l] = v.w;
        }
        const float4* gsrc = (const float4*)(Gg + ((size_t)b * NCH + ch + 1) * (CC * CC));
        #pragma unroll
        for (int q = 0; q < 4; ++q) ((float4*)GS[ng])[q * 64 + l] = gsrc[q * 64 + l];
        if (l < CC) thr2S[ng][l] = thr2_all[gbase + (ch + 1) * CC + l];
        else        invS[nb][l - CC] = inv_all[gbase + (ch + 1) * CC + (l - CC)];
      }
    } else {
      if (ch > 0) {
        // C(ch-1): M += (cst*inv) (x) k(ch-1)
        #pragma unroll
        for (int s = 0; s < CC; ++s) {
          const float2 cc = *(const float2*)&cstS[s * 64 + r0];
          const float iv = invS[pb][s];
          const float c0 = cc.x * iv, c1 = cc.y * iv;
          const float* kr = &kS[pb][s * 68 + jb];
          #pragma unroll
          for (int q = 0; q < 4; ++q) {
            const float4 kv = ((const float4*)kr)[q];
            M0[4*q+0] = fmaf(c0, kv.x, M0[4*q+0]); M0[4*q+1] = fmaf(c0, kv.y, M0[4*q+1]);
            M0[4*q+2] = fmaf(c0, kv.z, M0[4*q+2]); M0[4*q+3] = fmaf(c0, kv.w, M0[4*q+3]);
            M1[4*q+0] = fmaf(c1, kv.x, M1[4*q+0]); M1[4*q+1] = fmaf(c1, kv.y, M1[4*q+1]);
            M1[4*q+2] = fmaf(c1, kv.z, M1[4*q+2]); M1[4*q+3] = fmaf(c1, kv.w, M1[4*q+3]);
          }
        }
      }
      // A2(ch): rS[t][rows] = (M . k_t) * inv_t
      #pragma unroll
      for (int t = 0; t < CC; ++t) {
        const float* kr = &kS[cb][t * 68 + jb];
        float p0a=0.f,p0b=0.f,p1a=0.f,p1b=0.f;
        #pragma unroll
        for (int q = 0; q < 4; ++q) {
          const float4 kv = ((const float4*)kr)[q];
          p0a = fmaf(M0[4*q+0], kv.x, p0a); p0b = fmaf(M0[4*q+1], kv.y, p0b);
          p0a = fmaf(M0[4*q+2], kv.z, p0a); p0b = fmaf(M0[4*q+3], kv.w, p0b);
          p1a = fmaf(M1[4*q+0], kv.x, p1a); p1b = fmaf(M1[4*q+1], kv.y, p1b);
          p1a = fmaf(M1[4*q+2], kv.z, p1a); p1b = fmaf(M1[4*q+3], kv.w, p1b);
        }
        float p0 = quad_sum(p0a + p0b);
        float p1 = quad_sum(p1a + p1b);
        const float iv = invS[cb][t];
        if (B4 == 0) *(float2*)&rS[t * 64 + r0] = make_float2(p0 * iv, p1 * iv);
      }
    }
    __syncthreads();

    // ---- phase B (wave 0 only) ----
    if (w == 0) {
      float acc[CC], th[CC];
      #pragma unroll
      for (int t = 0; t < CC; ++t) acc[t] = kS[cb][t * 68 + l] - rS[t * 64 + l];
      #pragma unroll
      for (int q = 0; q < 8; ++q) {
        const float4 v = ((const float4*)thr2S[cg])[q];
        th[4*q] = v.x; th[4*q+1] = v.y; th[4*q+2] = v.z; th[4*q+3] = v.w;
      }
      const bool lastch = (ch == NCH - 1);
      #pragma unroll
      for (int t = 0; t < CC; ++t) {
        const float err = acc[t];
        const float ne2 = wave_sum(err * err);
        bool gate = (ne2 >= th[t]);
        if (lastch && t == CC - 1) gate = false;   // token 1023 excluded
        const float c = gate ? err : 0.f;
        cstS[t * 64 + l] = c;
        #pragma unroll
        for (int u = t + 1; u < CC; ++u)
          acc[u] = fmaf(-GS[cg][t * CC + u], c, acc[u]);
      }
    }
    __syncthreads();
  }

  // ---- epilogue: C(31) + final read (helpers) ----
  if (w > 0) {
    const int pe = (NCH - 1) % 3;   // = 1
    #pragma unroll
    for (int s = 0; s < CC; ++s) {
      const float2 cc = *(const float2*)&cstS[s * 64 + r0];
      const float iv = invS[pe][s];
      const float c0 = cc.x * iv, c1 = cc.y * iv;
      const float* kr = &kS[pe][s * 68 + jb];
      #pragma unroll
      for (int q = 0; q < 4; ++q) {
        const float4 kv = ((const float4*)kr)[q];
        M0[4*q+0] = fmaf(c0, kv.x, M0[4*q+0]); M0[4*q+1] = fmaf(c0, kv.y, M0[4*q+1]);
        M0[4*q+2] = fmaf(c0, kv.z, M0[4*q+2]); M0[4*q+3] = fmaf(c0, kv.w, M0[4*q+3]);
        M1[4*q+0] = fmaf(c1, kv.x, M1[4*q+0]); M1[4*q+1] = fmaf(c1, kv.y, M1[4*q+1]);
        M1[4*q+2] = fmaf(c1, kv.z, M1[4*q+2]); M1[4*q+3] = fmaf(c1, kv.w, M1[4*q+3]);
      }
    }
    // read = M . q, q = raw k[1023]
    const float* kr = &kS[pe][(CC - 1) * 68 + jb];
    float p0a=0.f,p0b=0.f,p1a=0.f,p1b=0.f;
    #pragma unroll
    for (int q = 0; q < 4; ++q) {
      const float4 kv = ((const float4*)kr)[q];
      p0a = fmaf(M0[4*q+0], kv.x, p0a); p0b = fmaf(M0[4*q+1], kv.y, p0b);
      p0a = fmaf(M0[4*q+2], kv.z, p0a); p0b = fmaf(M0[4*q+3], kv.w, p0b);
      p1a = fmaf(M1[4*q+0], kv.x, p1a); p1b = fmaf(M1[4*q+1], kv.y, p1b);
      p1a = fmaf(M1[4*q+2], kv.z, p1a); p1b = fmaf(M1[4*q+3], kv.w, p1b);
    }
    float d0 = quad_sum(p0a + p0b);
    float d1 = quad_sum(p1a + p1b);
    if (B4 == 0) *(float2*)&readv[b * 64 + r0] = make_float2(d0, d1);
  }
}

// ---------- Kernel 4: r2T[i][b] = (read @ rpW + rpb)^T ----------
__global__ __launch_bounds__(64) void rproj_kernel(const float* __restrict__ readv,
    const float* __restrict__ rpW, const float* __restrict__ rpb, float* __restrict__ r2T)
{
  const int b = blockIdx.x, i = threadIdx.x;
  const float* rv = readv + b * 64;          // uniform -> s_load
  float acc = rpb[i];
  #pragma unroll
  for (int j = 0; j < 64; ++j)
    acc = fmaf(rv[j], rpW[j * 64 + i], acc);
  r2T[i * 64 + b] = acc;                      // feature-major
}

// ---------- Kernel 5: out = r2 @ outW + outb  (grid 125 x 256) ----------
__global__ __launch_bounds__(256, 1) void out_kernel(const float* __restrict__ r2T,
    const float* __restrict__ outW, const float* __restrict__ outb,
    float* __restrict__ out)
{
  const int v = blockIdx.x * 256 + threadIdx.x;
  float acc[64];
  #pragma unroll
  for (int b = 0; b < 64; ++b) acc[b] = 0.f;
  for (int k = 0; k < 64; ++k) {
    const float wv = outW[(size_t)k * NV + v];
    const float* rr = r2T + k * 64;           // uniform row -> s_load
    #pragma unroll
    for (int b = 0; b < 64; ++b)
      acc[b] = fmaf(rr[b], wv, acc[b]);
  }
  const float ob = outb[v];
  #pragma unroll
  for (int b = 0; b < 64; ++b)
    out[(size_t)b * NV + v] = acc[b] + ob;
}

extern "C" void kernel_launch(void* const* d_in, const int* in_sizes, int n_in,
                              void* d_out, int out_size, void* d_ws, size_t ws_size,
                              hipStream_t stream)
{
  const int*   seq   = (const int*)d_in[0];
  const float* embed = (const float*)d_in[1];
  const float* W1    = (const float*)d_in[2];
  const float* b1    = (const float*)d_in[3];
  const float* W2    = (const float*)d_in[4];
  const float* b2    = (const float*)d_in[5];
  const float* gam   = (const float*)d_in[6];
  const float* bet   = (const float*)d_in[7];
  const float* kpW   = (const float*)d_in[8];
  const float* rpW   = (const float*)d_in[9];
  const float* rpb   = (const float*)d_in[10];
  const float* outW  = (const float*)d_in[11];
  const float* outb  = (const float*)d_in[12];
  float* out = (float*)d_out;

  float* ws = (float*)d_ws;
  float* kallT = ws;                                    // 4,194,304 f  [i][tok]
  float* G     = kallT + (size_t)HDIM * NT;             // 2,097,152 f
  float* thr2  = G     + (size_t)NB * NCH * CC * CC;    //    65,536 f
  float* inv   = thr2  + NT;                            //    65,536 f
  float* readv = inv   + NT;                            //     4,096 f
  float* r2T   = readv + NB * HDIM;                     //     4,096 f
  float* W1T   = r2T   + NB * HDIM;                     //     8,192 f
  float* kpWT  = W1T   + 8192;                          //     4,096 f

  hipLaunchKernelGGL(transpose_w, dim3(48), dim3(256), 0, stream, W1, kpW, W1T, kpWT);
  hipLaunchKernelGGL(tok4, dim3(256), dim3(256), 0, stream,
                     seq, embed, W1T, b1, W2, b2, gam, bet, kpWT, kallT, thr2, inv);
  hipLaunchKernelGGL(gram2, dim3(NB * NCH), dim3(64), 0, stream, kallT, inv, G);
  hipLaunchKernelGGL(scan5, dim3(NB), dim3(192), 0, stream, kallT, thr2, inv, G, readv);
  hipLaunchKernelGGL(rproj_kernel, dim3(NB), dim3(64), 0, stream, readv, rpW, rpb, r2T);
  hipLaunchKernelGGL(out_kernel, dim3(NV / 256), dim3(256), 0, stream, r2T, outW, outb, out);
}

// Round 6
// 483.692 us; speedup vs baseline: 1.2575x; 1.2575x over previous
//
#include <hip/hip_runtime.h>
#include <hip/hip_bf16.h>

#define HDIM 64
#define LSEQ 1024
#define NB 64
#define NV 32000
#define CC 32            // chunk length
#define NCH 32           // chunks per sequence
#define NT (NB * LSEQ)   // total tokens = kallT row stride

// ---------- DPP cross-lane sums (pure VALU) ----------
template<int CTRL>
__device__ __forceinline__ float dpp_red(float x) {
  int y = __builtin_amdgcn_update_dpp(0, __float_as_int(x), CTRL, 0xF, 0xF, true);
  return x + __int_as_float(y);
}
__device__ __forceinline__ float quad_sum(float x) {
  x = dpp_red<0xB1>(x);    // xor 1
  x = dpp_red<0x4E>(x);    // xor 2
  return x;
}
__device__ __forceinline__ float wave_sum(float x) {
  x = dpp_red<0xB1>(x);
  x = dpp_red<0x4E>(x);
  x = dpp_red<0x141>(x);   // row_half_mirror -> sum of 8
  x = dpp_red<0x140>(x);   // row_mirror      -> sum of 16
  float a = __int_as_float(__builtin_amdgcn_readlane(__float_as_int(x), 0));
  float b = __int_as_float(__builtin_amdgcn_readlane(__float_as_int(x), 16));
  float c = __int_as_float(__builtin_amdgcn_readlane(__float_as_int(x), 32));
  float d = __int_as_float(__builtin_amdgcn_readlane(__float_as_int(x), 48));
  return (a + b) + (c + d);
}

// ---------- Kernel 0: transpose W1 (64x128 -> 128x64) and kpW (64x64) ----------
__global__ __launch_bounds__(256) void transpose_w(const float* __restrict__ W1,
    const float* __restrict__ kpW, float* __restrict__ W1T, float* __restrict__ kpWT)
{
  const int tid = blockIdx.x * 256 + threadIdx.x;
  if (tid < 8192) { const int c = tid >> 6, j = tid & 63; W1T[tid] = W1[j * 128 + c]; }
  else { const int e = tid - 8192; const int i = e >> 6, j = e & 63; kpWT[e] = kpW[j * 64 + i]; }
}

// ---------- Kernel 1: token transform, lane = token ----------
__global__ __launch_bounds__(256, 1) void tok4(
    const int* __restrict__ seq, const float* __restrict__ embed,
    const float* __restrict__ W1T, const float* __restrict__ b1,
    const float* __restrict__ W2, const float* __restrict__ b2,
    const float* __restrict__ gamma, const float* __restrict__ beta,
    const float* __restrict__ kpWT, float* __restrict__ kallT,
    float* __restrict__ thr2_all, float* __restrict__ inv_all)
{
  const int tok = blockIdx.x * 256 + threadIdx.x;
  const int row = seq[tok];
  float h[64], x[64];
  const float4* ep = (const float4*)(embed + (size_t)row * HDIM);
  #pragma unroll
  for (int q = 0; q < 16; ++q) {
    const float4 v = ep[q];
    h[4*q] = v.x; h[4*q+1] = v.y; h[4*q+2] = v.z; h[4*q+3] = v.w;
  }
  #pragma unroll
  for (int j = 0; j < 64; ++j) x[j] = h[j] + b2[j];

  for (int c = 0; c < 128; ++c) {
    const float* w1r = W1T + c * 64;                   // uniform row -> s_load
    float a0 = 0.f, a1 = 0.f, a2 = 0.f, a3 = 0.f;
    #pragma unroll
    for (int j = 0; j < 64; j += 4) {
      a0 = fmaf(h[j],   w1r[j],   a0);
      a1 = fmaf(h[j+1], w1r[j+1], a1);
      a2 = fmaf(h[j+2], w1r[j+2], a2);
      a3 = fmaf(h[j+3], w1r[j+3], a3);
    }
    const float y = fmaxf(b1[c] + ((a0 + a1) + (a2 + a3)), 0.f);
    const float* w2r = W2 + c * 64;
    #pragma unroll
    for (int j = 0; j < 64; ++j) x[j] = fmaf(y, w2r[j], x[j]);
  }

  float s0=0.f,s1=0.f,s2=0.f,s3=0.f,q0=0.f,q1=0.f,q2=0.f,q3=0.f;
  #pragma unroll
  for (int j = 0; j < 64; j += 4) {
    s0 += x[j]; s1 += x[j+1]; s2 += x[j+2]; s3 += x[j+3];
    q0 = fmaf(x[j],   x[j],   q0); q1 = fmaf(x[j+1], x[j+1], q1);
    q2 = fmaf(x[j+2], x[j+2], q2); q3 = fmaf(x[j+3], x[j+3], q3);
  }
  const float mu  = ((s0+s1)+(s2+s3)) * (1.f/64.f);
  const float var = ((q0+q1)+(q2+q3)) * (1.f/64.f) - mu * mu;
  const float rs  = rsqrtf(var + 1e-5f);
  #pragma unroll
  for (int j = 0; j < 64; ++j) h[j] = (x[j] - mu) * rs * gamma[j] + beta[j];

  float nk2 = 0.f;
  for (int i = 0; i < 64; ++i) {
    const float* kr = kpWT + i * 64;                   // uniform row -> s_load
    float c0=0.f,c1=0.f,c2=0.f,c3=0.f;
    #pragma unroll
    for (int j = 0; j < 64; j += 4) {
      c0 = fmaf(h[j],   kr[j],   c0);
      c1 = fmaf(h[j+1], kr[j+1], c1);
      c2 = fmaf(h[j+2], kr[j+2], c2);
      c3 = fmaf(h[j+3], kr[j+3], c3);
    }
    const float ki = (c0 + c1) + (c2 + c3);
    nk2 = fmaf(ki, ki, nk2);
    kallT[(size_t)i * NT + tok] = ki;
  }
  thr2_all[tok] = 0.16f * nk2;
  inv_all[tok]  = 1.f / fmaxf(sqrtf(nk2), 1e-12f);
}

// ---------- Kernel 2: per-chunk normalized Gram ----------
__global__ __launch_bounds__(64) void gram2(const float* __restrict__ kallT,
    const float* __restrict__ inv_all, float* __restrict__ Gg)
{
  const int bi = blockIdx.x;
  const int b = bi >> 5, ch = bi & 31;
  const int l = threadIdx.x;
  const int t0 = (l & 7) * 4, s0 = (l >> 3) * 4;
  const size_t gb = (size_t)b * LSEQ + ch * CC;
  float g00=0,g01=0,g02=0,g03=0, g10=0,g11=0,g12=0,g13=0;
  float g20=0,g21=0,g22=0,g23=0, g30=0,g31=0,g32=0,g33=0;
  for (int j = 0; j < 64; ++j) {
    const float* rowp = kallT + (size_t)j * NT + gb;
    const float4 a = *(const float4*)(rowp + t0);
    const float4 c = *(const float4*)(rowp + s0);
    g00=fmaf(a.x,c.x,g00); g01=fmaf(a.x,c.y,g01); g02=fmaf(a.x,c.z,g02); g03=fmaf(a.x,c.w,g03);
    g10=fmaf(a.y,c.x,g10); g11=fmaf(a.y,c.y,g11); g12=fmaf(a.y,c.z,g12); g13=fmaf(a.y,c.w,g13);
    g20=fmaf(a.z,c.x,g20); g21=fmaf(a.z,c.y,g21); g22=fmaf(a.z,c.z,g22); g23=fmaf(a.z,c.w,g23);
    g30=fmaf(a.w,c.x,g30); g31=fmaf(a.w,c.y,g31); g32=fmaf(a.w,c.z,g32); g33=fmaf(a.w,c.w,g33);
  }
  const float4 it = *(const float4*)(inv_all + gb + t0);
  const float4 is = *(const float4*)(inv_all + gb + s0);
  float* Go = Gg + (size_t)bi * (CC * CC);
  float4 o;
  o.x=g00*it.x*is.x; o.y=g01*it.x*is.y; o.z=g02*it.x*is.z; o.w=g03*it.x*is.w;
  *(float4*)(Go + (t0+0)*CC + s0) = o;
  o.x=g10*it.y*is.x; o.y=g11*it.y*is.y; o.z=g12*it.y*is.z; o.w=g13*it.y*is.w;
  *(float4*)(Go + (t0+1)*CC + s0) = o;
  o.x=g20*it.z*is.x; o.y=g21*it.z*is.y; o.z=g22*it.z*is.z; o.w=g23*it.z*is.w;
  *(float4*)(Go + (t0+2)*CC + s0) = o;
  o.x=g30*it.w*is.x; o.y=g31*it.w*is.y; o.z=g32*it.w*is.z; o.w=g33*it.w*is.w;
  *(float4*)(Go + (t0+3)*CC + s0) = o;
}

// ---------- Kernel 3: chunked gated delta scan, 8-token pipelined phases ----------
// wave 0: serial gate core (B) + staging; waves 1-2: helpers (A2 base / C update),
// each owning 32 M rows as 2 rows x 16 cols per lane.
__global__ __launch_bounds__(192, 1) void scan6(
    const float* __restrict__ kallT, const float* __restrict__ thr2_all,
    const float* __restrict__ inv_all, const float* __restrict__ Gg,
    float* __restrict__ readv)
{
  __shared__ float kS[3][CC * 68];
  __shared__ float GS[2][CC * CC];
  __shared__ float rS[CC * 64];
  __shared__ float cstS[CC * 64];
  __shared__ float thr2S[2][CC];
  __shared__ float invS[3][CC];

  const int b = blockIdx.x, tid = threadIdx.x;
  const int w = tid >> 6, l = tid & 63;
  const int A = l >> 2, B4 = l & 3;
  const int r0 = 32 * (w - 1) + 2 * A;   // helper rows (w>0)
  const int jb = 16 * B4;
  const size_t gbase = (size_t)b * LSEQ;

  float M0[16], M1[16], acc[32];
  #pragma unroll
  for (int q = 0; q < 16; ++q) { M0[q] = 0.f; M1[q] = 0.f; }

// A2: rS[t][r0,r0+1] = (M . k_t) * inv_t for t in [T0,T0+8)
#define A2_SLICE(KB, IB, T0) do {                                              \
    _Pragma("unroll")                                                          \
    for (int t = (T0); t < (T0) + 8; ++t) {                                    \
      const float* kr = &kS[KB][t * 68 + jb];                                  \
      float p0a=0.f,p0b=0.f,p1a=0.f,p1b=0.f;                                   \
      _Pragma("unroll")                                                        \
      for (int q2 = 0; q2 < 4; ++q2) {                                         \
        const float4 kv = ((const float4*)kr)[q2];                             \
        p0a = fmaf(M0[4*q2+0], kv.x, p0a); p0b = fmaf(M0[4*q2+1], kv.y, p0b);  \
        p0a = fmaf(M0[4*q2+2], kv.z, p0a); p0b = fmaf(M0[4*q2+3], kv.w, p0b);  \
        p1a = fmaf(M1[4*q2+0], kv.x, p1a); p1b = fmaf(M1[4*q2+1], kv.y, p1b);  \
        p1a = fmaf(M1[4*q2+2], kv.z, p1a); p1b = fmaf(M1[4*q2+3], kv.w, p1b);  \
      }                                                                        \
      float p0 = quad_sum(p0a + p0b);                                          \
      float p1 = quad_sum(p1a + p1b);                                          \
      const float iv = invS[IB][t];                                            \
      if (B4 == 0) *(float2*)&rS[t * 64 + r0] = make_float2(p0 * iv, p1 * iv); \
    }                                                                          \
  } while (0)

// C: M += (cstS[s]*inv[s]) (x) k_s for s in [S0,S0+8)
#define C_SLICE(KB, IB, S0) do {                                               \
    _Pragma("unroll")                                                          \
    for (int s = (S0); s < (S0) + 8; ++s) {                                    \
      const float2 cc2 = *(const float2*)&cstS[s * 64 + r0];                   \
      const float iv = invS[IB][s];                                            \
      const float c0 = cc2.x * iv, c1 = cc2.y * iv;                            \
      const float* kr = &kS[KB][s * 68 + jb];                                  \
      _Pragma("unroll")                                                        \
      for (int q2 = 0; q2 < 4; ++q2) {                                         \
        const float4 kv = ((const float4*)kr)[q2];                             \
        M0[4*q2+0] = fmaf(c0, kv.x, M0[4*q2+0]); M0[4*q2+1] = fmaf(c0, kv.y, M0[4*q2+1]); \
        M0[4*q2+2] = fmaf(c0, kv.z, M0[4*q2+2]); M0[4*q2+3] = fmaf(c0, kv.w, M0[4*q2+3]); \
        M1[4*q2+0] = fmaf(c1, kv.x, M1[4*q2+0]); M1[4*q2+1] = fmaf(c1, kv.y, M1[4*q2+1]); \
        M1[4*q2+2] = fmaf(c1, kv.z, M1[4*q2+2]); M1[4*q2+3] = fmaf(c1, kv.w, M1[4*q2+3]); \
      }                                                                        \
    }                                                                          \
  } while (0)

// B: serial gate core, tokens [8Q, 8Q+8); G row register-loaded (8 x b128 broadcast)
#define B_SLICE(Q, CBUF, CGI, LASTCH) do {                                     \
    const int t0_ = 8 * (Q);                                                   \
    _Pragma("unroll")                                                          \
    for (int i = 0; i < 8; ++i) {                                              \
      const int u = t0_ + i;                                                   \
      acc[u] += kS[CBUF][u * 68 + l] - rS[u * 64 + l];                         \
    }                                                                          \
    const float4 tha = ((const float4*)&thr2S[CGI][t0_])[0];                   \
    const float4 thb = ((const float4*)&thr2S[CGI][t0_])[1];                   \
    const float th8[8] = {tha.x,tha.y,tha.z,tha.w, thb.x,thb.y,thb.z,thb.w};   \
    _Pragma("unroll")                                                          \
    for (int i = 0; i < 8; ++i) {                                              \
      const int t = t0_ + i;                                                   \
      float g[32];                                                             \
      const float4* gp = (const float4*)&GS[CGI][t * 32];                      \
      _Pragma("unroll")                                                        \
      for (int r = 0; r < 8; ++r) {                                            \
        const float4 v = gp[r];                                                \
        g[4*r]=v.x; g[4*r+1]=v.y; g[4*r+2]=v.z; g[4*r+3]=v.w;                  \
      }                                                                        \
      const float err = acc[t];                                                \
      const float ne2 = wave_sum(err * err);                                   \
      bool gate = (ne2 >= th8[i]);                                             \
      if ((LASTCH) && t == CC - 1) gate = false;                               \
      const float c = gate ? err : 0.f;                                        \
      cstS[t * 64 + l] = c;                                                    \
      _Pragma("unroll")                                                        \
      for (int u = 0; u < 32; ++u) acc[u] = fmaf(-g[u], c, acc[u]);            \
    }                                                                          \
  } while (0)

  // ---- prologue: stage chunk 0 ----
  if (w < 2) {
    const float* src = kallT + (size_t)l * NT + gbase + w * 16;
    #pragma unroll
    for (int q = 0; q < 4; ++q) {
      const float4 v = ((const float4*)src)[q];
      const int t0 = w * 16 + q * 4;
      kS[0][(t0+0)*68 + l] = v.x; kS[0][(t0+1)*68 + l] = v.y;
      kS[0][(t0+2)*68 + l] = v.z; kS[0][(t0+3)*68 + l] = v.w;
    }
  } else {
    const float4* gsrc = (const float4*)(Gg + (size_t)b * NCH * (CC * CC));
    #pragma unroll
    for (int q = 0; q < 4; ++q) ((float4*)GS[0])[q * 64 + l] = gsrc[q * 64 + l];
    if (l < CC) thr2S[0][l] = thr2_all[gbase + l];
    else        invS[0][l - CC] = inv_all[gbase + (l - CC)];
  }
  __syncthreads();

  for (int ch = 0; ch < NCH; ++ch) {
    const int cb = ch % 3, pb = (ch + 2) % 3, nb = (ch + 1) % 3;
    const int cg = ch & 1, ng = 1 - cg;
    const bool lastch = (ch == NCH - 1);

    // ---- P0: helpers: C(ch-1) tail + A2(ch) slice0 ; wave0: reset acc + stage ch+1 ----
    if (w == 0) {
      #pragma unroll
      for (int u = 0; u < 32; ++u) acc[u] = 0.f;
      if (!lastch) {
        const float* src = kallT + (size_t)l * NT + gbase + (ch + 1) * CC;
        #pragma unroll
        for (int q = 0; q < 8; ++q) {
          const float4 v = ((const float4*)src)[q];
          const int t0 = q * 4;
          kS[nb][(t0+0)*68 + l] = v.x; kS[nb][(t0+1)*68 + l] = v.y;
          kS[nb][(t0+2)*68 + l] = v.z; kS[nb][(t0+3)*68 + l] = v.w;
        }
        const float4* gsrc = (const float4*)(Gg + ((size_t)b * NCH + ch + 1) * (CC * CC));
        #pragma unroll
        for (int q = 0; q < 4; ++q) ((float4*)GS[ng])[q * 64 + l] = gsrc[q * 64 + l];
        if (l < CC) thr2S[ng][l] = thr2_all[gbase + (ch + 1) * CC + l];
        else        invS[nb][l - CC] = inv_all[gbase + (ch + 1) * CC + (l - CC)];
      }
    } else {
      if (ch > 0) C_SLICE(pb, pb, 24);
      A2_SLICE(cb, cb, 0);
    }
    __syncthreads();

    // ---- P1 ----
    if (w == 0) B_SLICE(0, cb, cg, lastch);
    else        A2_SLICE(cb, cb, 8);
    __syncthreads();
    // ---- P2 ----
    if (w == 0) B_SLICE(1, cb, cg, lastch);
    else        A2_SLICE(cb, cb, 16);
    __syncthreads();
    // ---- P3 ----
    if (w == 0) B_SLICE(2, cb, cg, lastch);
    else { A2_SLICE(cb, cb, 24); C_SLICE(cb, cb, 0); }
    __syncthreads();
    // ---- P4 ----
    if (w == 0) B_SLICE(3, cb, cg, lastch);
    else { C_SLICE(cb, cb, 8); C_SLICE(cb, cb, 16); }
    __syncthreads();
  }

  // ---- epilogue: C(31) tail + final read (helpers) ----
  {
    constexpr int fb = (NCH - 1) % 3;   // = 1
    if (w > 0) {
      C_SLICE(fb, fb, 24);
      const float* kr = &kS[fb][(CC - 1) * 68 + jb];
      float p0a=0.f,p0b=0.f,p1a=0.f,p1b=0.f;
      #pragma unroll
      for (int q2 = 0; q2 < 4; ++q2) {
        const float4 kv = ((const float4*)kr)[q2];
        p0a = fmaf(M0[4*q2+0], kv.x, p0a); p0b = fmaf(M0[4*q2+1], kv.y, p0b);
        p0a = fmaf(M0[4*q2+2], kv.z, p0a); p0b = fmaf(M0[4*q2+3], kv.w, p0b);
        p1a = fmaf(M1[4*q2+0], kv.x, p1a); p1b = fmaf(M1[4*q2+1], kv.y, p1b);
        p1a = fmaf(M1[4*q2+2], kv.z, p1a); p1b = fmaf(M1[4*q2+3], kv.w, p1b);
      }
      float d0 = quad_sum(p0a + p0b);
      float d1 = quad_sum(p1a + p1b);
      if (B4 == 0) *(float2*)&readv[b * 64 + r0] = make_float2(d0, d1);
    }
  }
#undef A2_SLICE
#undef C_SLICE
#undef B_SLICE
}

// ---------- Kernel 4: r2T[i][b] = (read @ rpW + rpb)^T ----------
__global__ __launch_bounds__(64) void rproj_kernel(const float* __restrict__ readv,
    const float* __restrict__ rpW, const float* __restrict__ rpb, float* __restrict__ r2T)
{
  const int b = blockIdx.x, i = threadIdx.x;
  const float* rv = readv + b * 64;
  float acc = rpb[i];
  #pragma unroll
  for (int j = 0; j < 64; ++j)
    acc = fmaf(rv[j], rpW[j * 64 + i], acc);
  r2T[i * 64 + b] = acc;
}

// ---------- Kernel 5: out = r2 @ outW + outb ----------
__global__ __launch_bounds__(256, 1) void out_kernel(const float* __restrict__ r2T,
    const float* __restrict__ outW, const float* __restrict__ outb,
    float* __restrict__ out)
{
  const int v = blockIdx.x * 256 + threadIdx.x;
  float acc[64];
  #pragma unroll
  for (int b = 0; b < 64; ++b) acc[b] = 0.f;
  for (int k = 0; k < 64; ++k) {
    const float wv = outW[(size_t)k * NV + v];
    const float* rr = r2T + k * 64;           // uniform row -> s_load
    #pragma unroll
    for (int b = 0; b < 64; ++b)
      acc[b] = fmaf(rr[b], wv, acc[b]);
  }
  const float ob = outb[v];
  #pragma unroll
  for (int b = 0; b < 64; ++b)
    out[(size_t)b * NV + v] = acc[b] + ob;
}

extern "C" void kernel_launch(void* const* d_in, const int* in_sizes, int n_in,
                              void* d_out, int out_size, void* d_ws, size_t ws_size,
                              hipStream_t stream)
{
  const int*   seq   = (const int*)d_in[0];
  const float* embed = (const float*)d_in[1];
  const float* W1    = (const float*)d_in[2];
  const float* b1    = (const float*)d_in[3];
  const float* W2    = (const float*)d_in[4];
  const float* b2    = (const float*)d_in[5];
  const float* gam   = (const float*)d_in[6];
  const float* bet   = (const float*)d_in[7];
  const float* kpW   = (const float*)d_in[8];
  const float* rpW   = (const float*)d_in[9];
  const float* rpb   = (const float*)d_in[10];
  const float* outW  = (const float*)d_in[11];
  const float* outb  = (const float*)d_in[12];
  float* out = (float*)d_out;

  float* ws = (float*)d_ws;
  float* kallT = ws;                                    // 4,194,304 f  [feat][tok]
  float* G     = kallT + (size_t)HDIM * NT;             // 2,097,152 f
  float* thr2  = G     + (size_t)NB * NCH * CC * CC;    //    65,536 f
  float* inv   = thr2  + NT;                            //    65,536 f
  float* readv = inv   + NT;                            //     4,096 f
  float* r2T   = readv + NB * HDIM;                     //     4,096 f
  float* W1T   = r2T   + NB * HDIM;                     //     8,192 f
  float* kpWT  = W1T   + 8192;                          //     4,096 f

  hipLaunchKernelGGL(transpose_w, dim3(48), dim3(256), 0, stream, W1, kpW, W1T, kpWT);
  hipLaunchKernelGGL(tok4, dim3(256), dim3(256), 0, stream,
                     seq, embed, W1T, b1, W2, b2, gam, bet, kpWT, kallT, thr2, inv);
  hipLaunchKernelGGL(gram2, dim3(NB * NCH), dim3(64), 0, stream, kallT, inv, G);
  hipLaunchKernelGGL(scan6, dim3(NB), dim3(192), 0, stream, kallT, thr2, inv, G, readv);
  hipLaunchKernelGGL(rproj_kernel, dim3(NB), dim3(64), 0, stream, readv, rpW, rpb, r2T);
  hipLaunchKernelGGL(out_kernel, dim3(NV / 256), dim3(256), 0, stream, r2T, outW, outb, out);
}